// Round 3
// baseline (390.989 us; speedup 1.0000x reference)
//
#include <hip/hip_runtime.h>
#include <hip/hip_bf16.h>
#include <stdint.h>

// Problem sizes (compile-time)
static constexpr int BATCH = 32768;
static constexpr int DIN   = 512;
static constexpr int DHID  = 1024;
static constexpr int DOUT  = 2048;

typedef __bf16 bf16x8  __attribute__((ext_vector_type(8)));
typedef float  f32x4   __attribute__((ext_vector_type(4)));
typedef float  f32x16  __attribute__((ext_vector_type(16)));

// fp32 -> bf16 round-to-nearest-even
__device__ __forceinline__ unsigned short f2bf(float f) {
    unsigned int u = __float_as_uint(f);
    u += 0x7FFFu + ((u >> 16) & 1u);
    return (unsigned short)(u >> 16);
}

// async global->LDS, 16B per lane. LDS dest = wave-uniform base + 16*lane.
__device__ __forceinline__ void gload_lds16(const void* g, void* l) {
    __builtin_amdgcn_global_load_lds((__attribute__((address_space(1))) void*)g,
                                     (__attribute__((address_space(3))) void*)l,
                                     16, 0, 0);
}

// ---------------------------------------------------------------------------
// Kernel 1: convert l1_w, weight fp32 -> bf16 (x is converted inside gemm1)
// ---------------------------------------------------------------------------
__global__ __launch_bounds__(256) void cvt_kernel(
    const float4* __restrict__ w1, const float4* __restrict__ w2,
    ushort4* __restrict__ w1b, ushort4* __restrict__ w2b) {
    const size_t NW1 = (size_t)DHID * DIN  / 4;   // 131,072
    const size_t NW2 = (size_t)DOUT * DHID / 4;   // 524,288
    size_t g = (size_t)blockIdx.x * blockDim.x + threadIdx.x;
    const float4* s; ushort4* d; size_t i;
    if (g < NW1)            { s = w1; d = w1b; i = g; }
    else if (g < NW1 + NW2) { s = w2; d = w2b; i = g - NW1; }
    else return;
    float4 v = s[i];
    ushort4 o;
    o.x = f2bf(v.x); o.y = f2bf(v.y); o.z = f2bf(v.z); o.w = f2bf(v.w);
    d[i] = o;
}

// ---------------------------------------------------------------------------
// GEMM1: h = x(fp32) * l1_w^T + l1_b, output bf16 [BATCH, DHID]
// 128x128 block, 4 waves 2x2, wave = 64x64 via 2x2 mfma_32x32x16, BK=32.
// A staged as fp32 via global_load_lds (fused convert on LDS->reg read).
// ---------------------------------------------------------------------------
__global__ __launch_bounds__(256) void gemm1_kernel(
    const float* __restrict__ A,            // x fp32 [BATCH, DIN]
    const unsigned short* __restrict__ Bw,  // l1_w bf16 [DHID, DIN]
    const float* __restrict__ l1b,          // [DHID]
    unsigned short* __restrict__ H) {       // out bf16 [BATCH, DHID]
    constexpr int K = DIN;
    __shared__ __align__(16) float          sAf[128 * 32];  // 16 KB
    __shared__ __align__(16) unsigned short sB [128 * 32];  //  8 KB

    const int tid  = threadIdx.x;
    const int lane = tid & 63;
    const int wid  = tid >> 6;
    const int wr = wid >> 1, wc = wid & 1;
    const int l31 = lane & 31, half = lane >> 5;
    const int blockM = blockIdx.x * 128;
    const int blockN = blockIdx.y * 128;

    // A staging (fp32): 4 issues/wave, 8 rows (128B/row) per issue
    const int arowInIssue = lane >> 3;           // 0..7
    const int acolf       = (lane & 7) * 4;      // float col, 16B chunks
    // B staging (bf16): 2 issues/wave, 16 rows (64B/row) per issue
    const int c0    = wid * 2;
    const int brow0 = c0 * 16 + (lane >> 2);
    const int bcol  = (lane & 3) * 8;
    const size_t bbase = (size_t)(blockN + brow0) * K + bcol;

    f32x16 acc[2][2];
#pragma unroll
    for (int mt = 0; mt < 2; ++mt)
#pragma unroll
        for (int nt = 0; nt < 2; ++nt)
#pragma unroll
            for (int i = 0; i < 16; ++i) acc[mt][nt][i] = 0.f;

    for (int k0 = 0; k0 < K; k0 += 32) {
#pragma unroll
        for (int j = 0; j < 4; ++j) {
            const int rowT = wid * 32 + j * 8;
            gload_lds16(A + (size_t)(blockM + rowT + arowInIssue) * K + acolf + k0,
                        sAf + rowT * 32);
        }
        gload_lds16(Bw + bbase + k0,          sB + c0 * 512);
        gload_lds16(Bw + bbase + 16 * K + k0, sB + c0 * 512 + 512);
        __syncthreads();

        bf16x8 af[2][2], bf[2][2];  // [tile][kstep]
#pragma unroll
        for (int mt = 0; mt < 2; ++mt)
#pragma unroll
            for (int ks = 0; ks < 2; ++ks) {
                const float* p = &sAf[(wr * 64 + mt * 32 + l31) * 32 + ks * 16 + half * 8];
                f32x4 a0 = *(const f32x4*)p;
                f32x4 a1 = *(const f32x4*)(p + 4);
                bf16x8 v;
#pragma unroll
                for (int i = 0; i < 4; ++i) { v[i] = (__bf16)a0[i]; v[4 + i] = (__bf16)a1[i]; }
                af[mt][ks] = v;
            }
#pragma unroll
        for (int nt = 0; nt < 2; ++nt)
#pragma unroll
            for (int ks = 0; ks < 2; ++ks)
                bf[nt][ks] = *(const bf16x8*)&sB[(wc * 64 + nt * 32 + l31) * 32 + ks * 16 + half * 8];

#pragma unroll
        for (int ks = 0; ks < 2; ++ks)
#pragma unroll
            for (int mt = 0; mt < 2; ++mt)
#pragma unroll
                for (int nt = 0; nt < 2; ++nt)
                    acc[mt][nt] = __builtin_amdgcn_mfma_f32_32x32x16_bf16(
                        af[mt][ks], bf[nt][ks], acc[mt][nt], 0, 0, 0);
        __syncthreads();
    }

    // Epilogue. 32x32 C/D layout: col = lane&31, row = 4*(lane>>5) + (reg&3) + 8*(reg>>2)
    const int colBase = blockN + wc * 64;
    const int rowBase = blockM + wr * 64;
    float bv[2];
#pragma unroll
    for (int nt = 0; nt < 2; ++nt) bv[nt] = l1b[colBase + nt * 32 + l31];
#pragma unroll
    for (int mt = 0; mt < 2; ++mt)
#pragma unroll
        for (int nt = 0; nt < 2; ++nt) {
            const int col = colBase + nt * 32 + l31;
#pragma unroll
            for (int reg = 0; reg < 16; ++reg) {
                const int row = rowBase + mt * 32 + 4 * half + (reg & 3) + 8 * (reg >> 2);
                H[(size_t)row * DHID + col] = f2bf(acc[mt][nt][reg] + bv[nt]);
            }
        }
}

// ---------------------------------------------------------------------------
// GEMM2: scores = H * weight^T + bias, fused per-block row-max.
// Same tile structure, both operands bf16.
// partials[row*32 + blockIdx.y*2 + wc] = max over this wave's 64 cols
// ---------------------------------------------------------------------------
__global__ __launch_bounds__(256) void gemm2_kernel(
    const unsigned short* __restrict__ A,   // H bf16 [BATCH, DHID]
    const unsigned short* __restrict__ Bw,  // weight bf16 [DOUT, DHID]
    const float* __restrict__ bias,         // [DOUT]
    float* __restrict__ partials) {         // [BATCH, 32]
    constexpr int K = DHID;
    __shared__ __align__(16) unsigned short sA[128 * 32];
    __shared__ __align__(16) unsigned short sB[128 * 32];

    const int tid  = threadIdx.x;
    const int lane = tid & 63;
    const int wid  = tid >> 6;
    const int wr = wid >> 1, wc = wid & 1;
    const int l31 = lane & 31, half = lane >> 5;
    const int blockM = blockIdx.x * 128;
    const int blockN = blockIdx.y * 128;

    const int c0    = wid * 2;
    const int arow0 = c0 * 16 + (lane >> 2);
    const int acol  = (lane & 3) * 8;
    const size_t abase = (size_t)(blockM + arow0) * K + acol;
    const size_t bbase = (size_t)(blockN + arow0) * K + acol;

    f32x16 acc[2][2];
#pragma unroll
    for (int mt = 0; mt < 2; ++mt)
#pragma unroll
        for (int nt = 0; nt < 2; ++nt)
#pragma unroll
            for (int i = 0; i < 16; ++i) acc[mt][nt][i] = 0.f;

    for (int k0 = 0; k0 < K; k0 += 32) {
        gload_lds16(A  + abase + k0,          sA + c0 * 512);
        gload_lds16(A  + abase + 16 * K + k0, sA + c0 * 512 + 512);
        gload_lds16(Bw + bbase + k0,          sB + c0 * 512);
        gload_lds16(Bw + bbase + 16 * K + k0, sB + c0 * 512 + 512);
        __syncthreads();

        bf16x8 af[2][2], bf[2][2];
#pragma unroll
        for (int mt = 0; mt < 2; ++mt)
#pragma unroll
            for (int ks = 0; ks < 2; ++ks)
                af[mt][ks] = *(const bf16x8*)&sA[(wr * 64 + mt * 32 + l31) * 32 + ks * 16 + half * 8];
#pragma unroll
        for (int nt = 0; nt < 2; ++nt)
#pragma unroll
            for (int ks = 0; ks < 2; ++ks)
                bf[nt][ks] = *(const bf16x8*)&sB[(wc * 64 + nt * 32 + l31) * 32 + ks * 16 + half * 8];

#pragma unroll
        for (int ks = 0; ks < 2; ++ks)
#pragma unroll
            for (int mt = 0; mt < 2; ++mt)
#pragma unroll
                for (int nt = 0; nt < 2; ++nt)
                    acc[mt][nt] = __builtin_amdgcn_mfma_f32_32x32x16_bf16(
                        af[mt][ks], bf[nt][ks], acc[mt][nt], 0, 0, 0);
        __syncthreads();
    }

    // Epilogue: +bias, max over nt, then reduce over the 32 lanes holding cols.
    const int colBase = blockN + wc * 64;
    const int rowBase = blockM + wr * 64;
    float bv[2];
#pragma unroll
    for (int nt = 0; nt < 2; ++nt) bv[nt] = bias[colBase + nt * 32 + l31];

    float mx[2][16];  // [mt][reg]
#pragma unroll
    for (int mt = 0; mt < 2; ++mt)
#pragma unroll
        for (int reg = 0; reg < 16; ++reg)
            mx[mt][reg] = fmaxf(acc[mt][0][reg] + bv[0], acc[mt][1][reg] + bv[1]);

    // cols live in lane&31; rows in (lane>>5, reg). offsets 1..16 keep lane>>5 fixed.
#pragma unroll
    for (int off = 1; off < 32; off <<= 1)
#pragma unroll
        for (int mt = 0; mt < 2; ++mt)
#pragma unroll
            for (int reg = 0; reg < 16; ++reg)
                mx[mt][reg] = fmaxf(mx[mt][reg], __shfl_xor(mx[mt][reg], off));

    if (l31 == 0) {
#pragma unroll
        for (int mt = 0; mt < 2; ++mt)
#pragma unroll
            for (int reg = 0; reg < 16; ++reg) {
                const int row = rowBase + mt * 32 + 4 * half + (reg & 3) + 8 * (reg >> 2);
                partials[(size_t)row * 32 + blockIdx.y * 2 + wc] = mx[mt][reg];
            }
    }
}

// ---------------------------------------------------------------------------
// Kernel 4: reduce 32 partials per row -> final max
// ---------------------------------------------------------------------------
__global__ __launch_bounds__(256) void reduce_kernel(
    const float4* __restrict__ partials, float* __restrict__ out) {
    const int row = blockIdx.x * blockDim.x + threadIdx.x;  // exactly BATCH threads
    const float4* p = partials + (size_t)row * 8;
    float m = -INFINITY;
#pragma unroll
    for (int i = 0; i < 8; ++i) {
        float4 v = p[i];
        m = fmaxf(m, fmaxf(fmaxf(v.x, v.y), fmaxf(v.z, v.w)));
    }
    out[row] = m;
}

// ---------------------------------------------------------------------------
extern "C" void kernel_launch(void* const* d_in, const int* in_sizes, int n_in,
                              void* d_out, int out_size, void* d_ws, size_t ws_size,
                              hipStream_t stream) {
    const float* x   = (const float*)d_in[0];
    const float* l1w = (const float*)d_in[1];
    const float* l1b = (const float*)d_in[2];
    const float* w2  = (const float*)d_in[3];
    const float* b2  = (const float*)d_in[4];
    float* out = (float*)d_out;

    char* ws = (char*)d_ws;
    // workspace layout (bytes)
    unsigned short* w1b = (unsigned short*)(ws);                 //  1 MB l1_w bf16
    unsigned short* w2b = (unsigned short*)(ws + 1048576);       //  4 MB weight bf16
    unsigned short* hb  = (unsigned short*)(ws + 5242880);       // 64 MB h bf16
    float* partials     = (float*)(ws + 72351744);               //  4 MB [BATCH,32]

    // 1) weight converts only (655,360 float4 groups)
    cvt_kernel<<<2560, 256, 0, stream>>>(
        (const float4*)l1w, (const float4*)w2, (ushort4*)w1b, (ushort4*)w2b);

    // 2) h = x @ l1_w^T + l1_b (x converted in-kernel)
    gemm1_kernel<<<dim3(BATCH / 128, DHID / 128), 256, 0, stream>>>(x, w1b, l1b, hb);

    // 3) scores = h @ weight^T + bias, fused per-block row-max
    gemm2_kernel<<<dim3(BATCH / 128, DOUT / 128), 256, 0, stream>>>(hb, w2b, b2, partials);

    // 4) final max over 32 partials per row
    reduce_kernel<<<BATCH / 256, 256, 0, stream>>>((const float4*)partials, out);
}

// Round 4
// 348.695 us; speedup vs baseline: 1.1213x; 1.1213x over previous
//
#include <hip/hip_runtime.h>
#include <hip/hip_bf16.h>
#include <stdint.h>

// Problem sizes (compile-time)
static constexpr int BATCH = 32768;
static constexpr int DIN   = 512;
static constexpr int DHID  = 1024;
static constexpr int DOUT  = 2048;

typedef __bf16 bf16x8  __attribute__((ext_vector_type(8)));
typedef float  f32x4   __attribute__((ext_vector_type(4)));
typedef float  f32x16  __attribute__((ext_vector_type(16)));

// fp32 -> bf16 round-to-nearest-even
__device__ __forceinline__ unsigned short f2bf(float f) {
    unsigned int u = __float_as_uint(f);
    u += 0x7FFFu + ((u >> 16) & 1u);
    return (unsigned short)(u >> 16);
}

// async global->LDS, 16B per lane. LDS dest = wave-uniform base + 16*lane.
__device__ __forceinline__ void gload_lds16(const void* g, void* l) {
    __builtin_amdgcn_global_load_lds((__attribute__((address_space(1))) void*)g,
                                     (__attribute__((address_space(3))) void*)l,
                                     16, 0, 0);
}

// ---------------------------------------------------------------------------
// Kernel 1: convert l1_w, weight fp32 -> bf16 (x is converted inside gemm1)
// ---------------------------------------------------------------------------
__global__ __launch_bounds__(256) void cvt_kernel(
    const float4* __restrict__ w1, const float4* __restrict__ w2,
    ushort4* __restrict__ w1b, ushort4* __restrict__ w2b) {
    const size_t NW1 = (size_t)DHID * DIN  / 4;   // 131,072
    const size_t NW2 = (size_t)DOUT * DHID / 4;   // 524,288
    size_t g = (size_t)blockIdx.x * blockDim.x + threadIdx.x;
    const float4* s; ushort4* d; size_t i;
    if (g < NW1)            { s = w1; d = w1b; i = g; }
    else if (g < NW1 + NW2) { s = w2; d = w2b; i = g - NW1; }
    else return;
    float4 v = s[i];
    ushort4 o;
    o.x = f2bf(v.x); o.y = f2bf(v.y); o.z = f2bf(v.z); o.w = f2bf(v.w);
    d[i] = o;
}

// ===========================================================================
// Swizzled LDS layouts (realized through the staging gather, since
// global_load_lds scatters lane i to base+16i):
//   bf16 tile: 128 rows x 32 elems = 4 chunks(16B)/row.
//     slot = row*4 + chunk',  chunk' = chunk ^ ((row>>1)&3)
//   fp32 tile: 128 rows x 32 elems = 8 chunks(16B)/row.
//     slot = row*8 + chunk',  chunk' = chunk ^ (row&7)
// Fragment reads apply the same XOR -> 8 lanes per 4-bank group (b128 floor).
// ===========================================================================

// ---------------------------------------------------------------------------
// GEMM1: h = x(fp32) * l1_w^T + l1_b, output bf16 [BATCH, DHID]
// 128x128 block, 4 waves 2x2, wave = 64x64 via 2x2 mfma_32x32x16, BK=32.
// ---------------------------------------------------------------------------
__global__ __launch_bounds__(256) void gemm1_kernel(
    const float* __restrict__ A,            // x fp32 [BATCH, DIN]
    const unsigned short* __restrict__ Bw,  // l1_w bf16 [DHID, DIN]
    const float* __restrict__ l1b,          // [DHID]
    unsigned short* __restrict__ H) {       // out bf16 [BATCH, DHID]
    constexpr int K = DIN;
    __shared__ __align__(16) float          sAf[128 * 32];  // 16 KB
    __shared__ __align__(16) unsigned short sB [128 * 32];  //  8 KB

    const int tid  = threadIdx.x;
    const int lane = tid & 63;
    const int wid  = tid >> 6;
    const int wr = wid >> 1, wc = wid & 1;
    const int l31 = lane & 31, half = lane >> 5;
    const int blockM = blockIdx.x * 128;
    const int blockN = blockIdx.y * 128;

    // --- A staging (fp32, swizzled): 4 issues/wave, 64 slots each ---
    int aRow[4]; size_t aGbl[4];
#pragma unroll
    for (int j = 0; j < 4; ++j) {
        const int slot = wid * 256 + j * 64 + lane;
        const int row  = slot >> 3;
        const int chp  = slot & 7;
        const int ch   = chp ^ (row & 7);
        aRow[j] = slot & ~63;  // issue base slot (wave-uniform per j)
        aGbl[j] = (size_t)(blockM + row) * K + ch * 4;
    }
    // --- B staging (bf16, swizzled): 2 issues/wave, 64 slots each ---
    size_t bGbl[2]; int bSlot0[2];
#pragma unroll
    for (int j = 0; j < 2; ++j) {
        const int slot = wid * 128 + j * 64 + lane;
        const int row  = slot >> 2;
        const int chp  = slot & 3;
        const int ch   = chp ^ ((row >> 1) & 3);
        bSlot0[j] = wid * 128 + j * 64;
        bGbl[j] = (size_t)(blockN + row) * K + ch * 8;
    }

    const int sw2 = (l31 >> 1) & 3;  // bf16 fragment swizzle key
    const int sw8 = l31 & 7;         // fp32 fragment swizzle key

    f32x16 acc[2][2];
#pragma unroll
    for (int mt = 0; mt < 2; ++mt)
#pragma unroll
        for (int nt = 0; nt < 2; ++nt)
#pragma unroll
            for (int i = 0; i < 16; ++i) acc[mt][nt][i] = 0.f;

    for (int k0 = 0; k0 < K; k0 += 32) {
#pragma unroll
        for (int j = 0; j < 4; ++j)
            gload_lds16(A + aGbl[j] + k0, sAf + aRow[j] * 4);
#pragma unroll
        for (int j = 0; j < 2; ++j)
            gload_lds16(Bw + bGbl[j] + k0, sB + bSlot0[j] * 8);
        __syncthreads();

        bf16x8 af[2][2], bf[2][2];  // [tile][kstep]
#pragma unroll
        for (int mt = 0; mt < 2; ++mt)
#pragma unroll
            for (int ks = 0; ks < 2; ++ks) {
                const int row = wr * 64 + mt * 32 + l31;
                const int c0  = (ks * 4 + half * 2) ^ sw8;      // first 16B chunk
                const int c1  = (ks * 4 + half * 2 + 1) ^ sw8;  // second 16B chunk
                f32x4 a0 = *(const f32x4*)&sAf[row * 32 + c0 * 4];
                f32x4 a1 = *(const f32x4*)&sAf[row * 32 + c1 * 4];
                bf16x8 v;
#pragma unroll
                for (int i = 0; i < 4; ++i) { v[i] = (__bf16)a0[i]; v[4 + i] = (__bf16)a1[i]; }
                af[mt][ks] = v;
            }
#pragma unroll
        for (int nt = 0; nt < 2; ++nt)
#pragma unroll
            for (int ks = 0; ks < 2; ++ks) {
                const int row = wc * 64 + nt * 32 + l31;
                const int ch  = (ks * 2 + half) ^ sw2;
                bf[nt][ks] = *(const bf16x8*)&sB[row * 32 + ch * 8];
            }

#pragma unroll
        for (int ks = 0; ks < 2; ++ks)
#pragma unroll
            for (int mt = 0; mt < 2; ++mt)
#pragma unroll
                for (int nt = 0; nt < 2; ++nt)
                    acc[mt][nt] = __builtin_amdgcn_mfma_f32_32x32x16_bf16(
                        af[mt][ks], bf[nt][ks], acc[mt][nt], 0, 0, 0);
        __syncthreads();
    }

    // Epilogue. 32x32 C/D layout: col = lane&31, row = 4*(lane>>5) + (reg&3) + 8*(reg>>2)
    const int colBase = blockN + wc * 64;
    const int rowBase = blockM + wr * 64;
    float bv[2];
#pragma unroll
    for (int nt = 0; nt < 2; ++nt) bv[nt] = l1b[colBase + nt * 32 + l31];
#pragma unroll
    for (int mt = 0; mt < 2; ++mt)
#pragma unroll
        for (int nt = 0; nt < 2; ++nt) {
            const int col = colBase + nt * 32 + l31;
#pragma unroll
            for (int reg = 0; reg < 16; ++reg) {
                const int row = rowBase + mt * 32 + 4 * half + (reg & 3) + 8 * (reg >> 2);
                H[(size_t)row * DHID + col] = f2bf(acc[mt][nt][reg] + bv[nt]);
            }
        }
}

// ---------------------------------------------------------------------------
// GEMM2: scores = H * weight^T + bias, fused per-block row-max.
// partials[row*32 + blockIdx.y*2 + wc] = max over this wave's 64 cols
// ---------------------------------------------------------------------------
__global__ __launch_bounds__(256) void gemm2_kernel(
    const unsigned short* __restrict__ A,   // H bf16 [BATCH, DHID]
    const unsigned short* __restrict__ Bw,  // weight bf16 [DOUT, DHID]
    const float* __restrict__ bias,         // [DOUT]
    float* __restrict__ partials) {         // [BATCH, 32]
    constexpr int K = DHID;
    __shared__ __align__(16) unsigned short sA[128 * 32];
    __shared__ __align__(16) unsigned short sB[128 * 32];

    const int tid  = threadIdx.x;
    const int lane = tid & 63;
    const int wid  = tid >> 6;
    const int wr = wid >> 1, wc = wid & 1;
    const int l31 = lane & 31, half = lane >> 5;
    const int blockM = blockIdx.x * 128;
    const int blockN = blockIdx.y * 128;

    // swizzled staging precompute: 2 issues/wave for each of A, B
    size_t aGbl[2], bGbl[2]; int slot0[2];
#pragma unroll
    for (int j = 0; j < 2; ++j) {
        const int slot = wid * 128 + j * 64 + lane;
        const int row  = slot >> 2;
        const int chp  = slot & 3;
        const int ch   = chp ^ ((row >> 1) & 3);
        slot0[j] = wid * 128 + j * 64;
        aGbl[j] = (size_t)(blockM + row) * K + ch * 8;
        bGbl[j] = (size_t)(blockN + row) * K + ch * 8;
    }
    const int sw2 = (l31 >> 1) & 3;

    f32x16 acc[2][2];
#pragma unroll
    for (int mt = 0; mt < 2; ++mt)
#pragma unroll
        for (int nt = 0; nt < 2; ++nt)
#pragma unroll
            for (int i = 0; i < 16; ++i) acc[mt][nt][i] = 0.f;

    for (int k0 = 0; k0 < K; k0 += 32) {
#pragma unroll
        for (int j = 0; j < 2; ++j) {
            gload_lds16(A  + aGbl[j] + k0, sA + slot0[j] * 8);
            gload_lds16(Bw + bGbl[j] + k0, sB + slot0[j] * 8);
        }
        __syncthreads();

        bf16x8 af[2][2], bf[2][2];
#pragma unroll
        for (int mt = 0; mt < 2; ++mt)
#pragma unroll
            for (int ks = 0; ks < 2; ++ks) {
                const int row = wr * 64 + mt * 32 + l31;
                const int ch  = (ks * 2 + half) ^ sw2;
                af[mt][ks] = *(const bf16x8*)&sA[row * 32 + ch * 8];
            }
#pragma unroll
        for (int nt = 0; nt < 2; ++nt)
#pragma unroll
            for (int ks = 0; ks < 2; ++ks) {
                const int row = wc * 64 + nt * 32 + l31;
                const int ch  = (ks * 2 + half) ^ sw2;
                bf[nt][ks] = *(const bf16x8*)&sB[row * 32 + ch * 8];
            }

#pragma unroll
        for (int ks = 0; ks < 2; ++ks)
#pragma unroll
            for (int mt = 0; mt < 2; ++mt)
#pragma unroll
                for (int nt = 0; nt < 2; ++nt)
                    acc[mt][nt] = __builtin_amdgcn_mfma_f32_32x32x16_bf16(
                        af[mt][ks], bf[nt][ks], acc[mt][nt], 0, 0, 0);
        __syncthreads();
    }

    // Epilogue: +bias, max over nt, then reduce over the 32 lanes holding cols.
    const int colBase = blockN + wc * 64;
    const int rowBase = blockM + wr * 64;
    float bv[2];
#pragma unroll
    for (int nt = 0; nt < 2; ++nt) bv[nt] = bias[colBase + nt * 32 + l31];

    float mx[2][16];  // [mt][reg]
#pragma unroll
    for (int mt = 0; mt < 2; ++mt)
#pragma unroll
        for (int reg = 0; reg < 16; ++reg)
            mx[mt][reg] = fmaxf(acc[mt][0][reg] + bv[0], acc[mt][1][reg] + bv[1]);

    // cols live in lane&31; rows in (lane>>5, reg). reduce across the 32 col-lanes.
#pragma unroll
    for (int off = 1; off < 32; off <<= 1)
#pragma unroll
        for (int mt = 0; mt < 2; ++mt)
#pragma unroll
            for (int reg = 0; reg < 16; ++reg)
                mx[mt][reg] = fmaxf(mx[mt][reg], __shfl_xor(mx[mt][reg], off));

    if (l31 == 0) {
#pragma unroll
        for (int mt = 0; mt < 2; ++mt)
#pragma unroll
            for (int reg = 0; reg < 16; ++reg) {
                const int row = rowBase + mt * 32 + 4 * half + (reg & 3) + 8 * (reg >> 2);
                partials[(size_t)row * 32 + blockIdx.y * 2 + wc] = mx[mt][reg];
            }
    }
}

// ---------------------------------------------------------------------------
// Kernel 4: reduce 32 partials per row -> final max
// ---------------------------------------------------------------------------
__global__ __launch_bounds__(256) void reduce_kernel(
    const float4* __restrict__ partials, float* __restrict__ out) {
    const int row = blockIdx.x * blockDim.x + threadIdx.x;  // exactly BATCH threads
    const float4* p = partials + (size_t)row * 8;
    float m = -INFINITY;
#pragma unroll
    for (int i = 0; i < 8; ++i) {
        float4 v = p[i];
        m = fmaxf(m, fmaxf(fmaxf(v.x, v.y), fmaxf(v.z, v.w)));
    }
    out[row] = m;
}

// ---------------------------------------------------------------------------
extern "C" void kernel_launch(void* const* d_in, const int* in_sizes, int n_in,
                              void* d_out, int out_size, void* d_ws, size_t ws_size,
                              hipStream_t stream) {
    const float* x   = (const float*)d_in[0];
    const float* l1w = (const float*)d_in[1];
    const float* l1b = (const float*)d_in[2];
    const float* w2  = (const float*)d_in[3];
    const float* b2  = (const float*)d_in[4];
    float* out = (float*)d_out;

    char* ws = (char*)d_ws;
    // workspace layout (bytes)
    unsigned short* w1b = (unsigned short*)(ws);                 //  1 MB l1_w bf16
    unsigned short* w2b = (unsigned short*)(ws + 1048576);       //  4 MB weight bf16
    unsigned short* hb  = (unsigned short*)(ws + 5242880);       // 64 MB h bf16
    float* partials     = (float*)(ws + 72351744);               //  4 MB [BATCH,32]

    // 1) weight converts only (655,360 float4 groups)
    cvt_kernel<<<2560, 256, 0, stream>>>(
        (const float4*)l1w, (const float4*)w2, (ushort4*)w1b, (ushort4*)w2b);

    // 2) h = x @ l1_w^T + l1_b (x converted in-kernel)
    gemm1_kernel<<<dim3(BATCH / 128, DHID / 128), 256, 0, stream>>>(x, w1b, l1b, hb);

    // 3) scores = h @ weight^T + bias, fused per-block row-max
    gemm2_kernel<<<dim3(BATCH / 128, DOUT / 128), 256, 0, stream>>>(hb, w2b, b2, partials);

    // 4) final max over 32 partials per row
    reduce_kernel<<<BATCH / 256, 256, 0, stream>>>((const float4*)partials, out);
}

// Round 5
// 339.294 us; speedup vs baseline: 1.1524x; 1.0277x over previous
//
#include <hip/hip_runtime.h>
#include <hip/hip_bf16.h>
#include <stdint.h>

// Problem sizes (compile-time)
static constexpr int BATCH = 32768;
static constexpr int DIN   = 512;
static constexpr int DHID  = 1024;
static constexpr int DOUT  = 2048;

typedef __bf16 bf16x8 __attribute__((ext_vector_type(8)));
typedef float  f32x4  __attribute__((ext_vector_type(4)));

// fp32 -> bf16 round-to-nearest-even
__device__ __forceinline__ unsigned short f2bf(float f) {
    unsigned int u = __float_as_uint(f);
    u += 0x7FFFu + ((u >> 16) & 1u);
    return (unsigned short)(u >> 16);
}

// async global->LDS, 16B per lane. LDS dest = wave-uniform base + 16*lane.
__device__ __forceinline__ void gload_lds16(const void* g, void* l) {
    __builtin_amdgcn_global_load_lds((__attribute__((address_space(1))) void*)g,
                                     (__attribute__((address_space(3))) void*)l,
                                     16, 0, 0);
}

// ---------------------------------------------------------------------------
// Kernel 1: convert x, l1_w, weight fp32 -> bf16 into workspace
// ---------------------------------------------------------------------------
__global__ __launch_bounds__(256) void cvt_kernel(
    const float4* __restrict__ x, const float4* __restrict__ w1, const float4* __restrict__ w2,
    ushort4* __restrict__ xb, ushort4* __restrict__ w1b, ushort4* __restrict__ w2b) {
    const size_t NX  = (size_t)BATCH * DIN  / 4;   // 4,194,304
    const size_t NW1 = (size_t)DHID  * DIN  / 4;   //   131,072
    const size_t NW2 = (size_t)DOUT  * DHID / 4;   //   524,288
    size_t g = (size_t)blockIdx.x * blockDim.x + threadIdx.x;
    const float4* s; ushort4* d; size_t i;
    if (g < NX)                  { s = x;  d = xb;  i = g; }
    else if (g < NX + NW1)       { s = w1; d = w1b; i = g - NX; }
    else if (g < NX + NW1 + NW2) { s = w2; d = w2b; i = g - NX - NW1; }
    else return;
    float4 v = s[i];
    ushort4 o;
    o.x = f2bf(v.x); o.y = f2bf(v.y); o.z = f2bf(v.z); o.w = f2bf(v.w);
    d[i] = o;
}

// ===========================================================================
// GEMM core: C[128x128] = A[M,K] * Bw[N,K]^T per block. 256 thr = 4 waves 2x2,
// wave = 64x64 via 4x4 mfma_16x16x32. BK=64 (two MFMA k-steps per barrier).
// LDS tile layout (both operands): 128 rows x 64 bf16 = 8 chunks(16B)/row,
// swizzled: slot(row, chunk) = row*8 + (chunk ^ (row&7)).
//   - staging: slot s -> row=s>>3, fetches chunk (s&7)^(row&7)  (128B-coalesced)
//   - fragment read lane(r=lane&15,q=lane>>4), kstep ks:
//       chunk = (ks*4+q) ^ (r&7)  -> 8 lanes per 4-bank group (b128 floor)
// Grid is N-fastest (blockIdx.x = N-tile) so co-resident blocks share the
// A M-tile and keep the small streamed weight resident in L2.
// ===========================================================================

// GEMM1: h = x * l1_w^T + l1_b, output bf16 [BATCH, DHID]
__global__ __launch_bounds__(256) void gemm1_kernel(
    const unsigned short* __restrict__ A,   // x bf16 [BATCH, DIN]
    const unsigned short* __restrict__ Bw,  // l1_w bf16 [DHID, DIN]
    const float* __restrict__ l1b,          // [DHID]
    unsigned short* __restrict__ H) {       // out bf16 [BATCH, DHID]
    constexpr int K = DIN;
    __shared__ __align__(16) unsigned short sA[128 * 64];  // 16 KB
    __shared__ __align__(16) unsigned short sB[128 * 64];  // 16 KB

    const int tid  = threadIdx.x;
    const int lane = tid & 63;
    const int wid  = tid >> 6;
    const int wr = wid >> 1, wc = wid & 1;
    const int r = lane & 15, q = lane >> 4;
    const int sw = r & 7;
    const int blockN = blockIdx.x * 128;   // N-fastest
    const int blockM = blockIdx.y * 128;

    // staging precompute: 4 issues/wave/operand, 64 slots each
    size_t aOff[4], bOff[4]; int sbase[4];
#pragma unroll
    for (int j = 0; j < 4; ++j) {
        const int s   = wid * 256 + j * 64 + lane;
        const int row = s >> 3;
        const int ch  = (s & 7) ^ (row & 7);
        sbase[j] = (wid * 256 + j * 64) * 8;             // elem offset of issue base
        aOff[j] = (size_t)(blockM + row) * K + ch * 8;
        bOff[j] = (size_t)(blockN + row) * K + ch * 8;
    }

    f32x4 acc[4][4];
#pragma unroll
    for (int mt = 0; mt < 4; ++mt)
#pragma unroll
        for (int nt = 0; nt < 4; ++nt) { f32x4 z = {0.f, 0.f, 0.f, 0.f}; acc[mt][nt] = z; }

    for (int k0 = 0; k0 < K; k0 += 64) {
#pragma unroll
        for (int j = 0; j < 4; ++j) {
            gload_lds16(A  + aOff[j] + k0, sA + sbase[j]);
            gload_lds16(Bw + bOff[j] + k0, sB + sbase[j]);
        }
        __syncthreads();
#pragma unroll
        for (int ks = 0; ks < 2; ++ks) {
            const int ch = ((ks << 2) + q) ^ sw;
            bf16x8 af[4], bf[4];
#pragma unroll
            for (int mt = 0; mt < 4; ++mt) af[mt] = *(const bf16x8*)&sA[(wr * 64 + mt * 16 + r) * 64 + ch * 8];
#pragma unroll
            for (int nt = 0; nt < 4; ++nt) bf[nt] = *(const bf16x8*)&sB[(wc * 64 + nt * 16 + r) * 64 + ch * 8];
#pragma unroll
            for (int mt = 0; mt < 4; ++mt)
#pragma unroll
                for (int nt = 0; nt < 4; ++nt)
                    acc[mt][nt] = __builtin_amdgcn_mfma_f32_16x16x32_bf16(af[mt], bf[nt], acc[mt][nt], 0, 0, 0);
        }
        __syncthreads();
    }

    // Epilogue: +bias, convert, store. C/D layout: col = lane&15, row = q*4+reg.
    const int colBase = blockN + wc * 64;
    const int rowBase = blockM + wr * 64;
    float bv[4];
#pragma unroll
    for (int nt = 0; nt < 4; ++nt) bv[nt] = l1b[colBase + nt * 16 + r];
#pragma unroll
    for (int mt = 0; mt < 4; ++mt) {
        const int row0 = rowBase + mt * 16 + q * 4;
#pragma unroll
        for (int nt = 0; nt < 4; ++nt) {
            const int col = colBase + nt * 16 + r;
#pragma unroll
            for (int reg = 0; reg < 4; ++reg)
                H[(size_t)(row0 + reg) * DHID + col] = f2bf(acc[mt][nt][reg] + bv[nt]);
        }
    }
}

// GEMM2: scores = H * weight^T + bias, fused row-max over this block's 128 cols.
__global__ __launch_bounds__(256) void gemm2_kernel(
    const unsigned short* __restrict__ A,   // H bf16 [BATCH, DHID]
    const unsigned short* __restrict__ Bw,  // weight bf16 [DOUT, DHID]
    const float* __restrict__ bias,         // [DOUT]
    float* __restrict__ partials) {         // [BATCH, 32]
    constexpr int K = DHID;
    __shared__ __align__(16) unsigned short sA[128 * 64];
    __shared__ __align__(16) unsigned short sB[128 * 64];

    const int tid  = threadIdx.x;
    const int lane = tid & 63;
    const int wid  = tid >> 6;
    const int wr = wid >> 1, wc = wid & 1;
    const int r = lane & 15, q = lane >> 4;
    const int sw = r & 7;
    const int blockN = blockIdx.x * 128;   // N-fastest
    const int blockM = blockIdx.y * 128;

    size_t aOff[4], bOff[4]; int sbase[4];
#pragma unroll
    for (int j = 0; j < 4; ++j) {
        const int s   = wid * 256 + j * 64 + lane;
        const int row = s >> 3;
        const int ch  = (s & 7) ^ (row & 7);
        sbase[j] = (wid * 256 + j * 64) * 8;
        aOff[j] = (size_t)(blockM + row) * K + ch * 8;
        bOff[j] = (size_t)(blockN + row) * K + ch * 8;
    }

    f32x4 acc[4][4];
#pragma unroll
    for (int mt = 0; mt < 4; ++mt)
#pragma unroll
        for (int nt = 0; nt < 4; ++nt) { f32x4 z = {0.f, 0.f, 0.f, 0.f}; acc[mt][nt] = z; }

    for (int k0 = 0; k0 < K; k0 += 64) {
#pragma unroll
        for (int j = 0; j < 4; ++j) {
            gload_lds16(A  + aOff[j] + k0, sA + sbase[j]);
            gload_lds16(Bw + bOff[j] + k0, sB + sbase[j]);
        }
        __syncthreads();
#pragma unroll
        for (int ks = 0; ks < 2; ++ks) {
            const int ch = ((ks << 2) + q) ^ sw;
            bf16x8 af[4], bf[4];
#pragma unroll
            for (int mt = 0; mt < 4; ++mt) af[mt] = *(const bf16x8*)&sA[(wr * 64 + mt * 16 + r) * 64 + ch * 8];
#pragma unroll
            for (int nt = 0; nt < 4; ++nt) bf[nt] = *(const bf16x8*)&sB[(wc * 64 + nt * 16 + r) * 64 + ch * 8];
#pragma unroll
            for (int mt = 0; mt < 4; ++mt)
#pragma unroll
                for (int nt = 0; nt < 4; ++nt)
                    acc[mt][nt] = __builtin_amdgcn_mfma_f32_16x16x32_bf16(af[mt], bf[nt], acc[mt][nt], 0, 0, 0);
        }
        __syncthreads();
    }

    // Epilogue: +bias, max over the wave's 64 cols, 16-lane reduce, write partial.
    const int colBase = blockN + wc * 64;
    const int rowBase = blockM + wr * 64;
    float bv[4];
#pragma unroll
    for (int nt = 0; nt < 4; ++nt) bv[nt] = bias[colBase + nt * 16 + r];

    float mx[4][4];  // [mt][reg]
#pragma unroll
    for (int mt = 0; mt < 4; ++mt)
#pragma unroll
        for (int reg = 0; reg < 4; ++reg) {
            float v = acc[mt][0][reg] + bv[0];
            v = fmaxf(v, acc[mt][1][reg] + bv[1]);
            v = fmaxf(v, acc[mt][2][reg] + bv[2]);
            v = fmaxf(v, acc[mt][3][reg] + bv[3]);
            mx[mt][reg] = v;
        }
#pragma unroll
    for (int off = 1; off < 16; off <<= 1)
#pragma unroll
        for (int mt = 0; mt < 4; ++mt)
#pragma unroll
            for (int reg = 0; reg < 4; ++reg)
                mx[mt][reg] = fmaxf(mx[mt][reg], __shfl_xor(mx[mt][reg], off));

    if (r == 0) {
#pragma unroll
        for (int mt = 0; mt < 4; ++mt)
#pragma unroll
            for (int reg = 0; reg < 4; ++reg) {
                const int row = rowBase + mt * 16 + q * 4 + reg;
                partials[(size_t)row * 32 + blockIdx.x * 2 + wc] = mx[mt][reg];
            }
    }
}

// ---------------------------------------------------------------------------
// Kernel 4: reduce 32 partials per row -> final max
// ---------------------------------------------------------------------------
__global__ __launch_bounds__(256) void reduce_kernel(
    const float4* __restrict__ partials, float* __restrict__ out) {
    const int row = blockIdx.x * blockDim.x + threadIdx.x;  // exactly BATCH threads
    const float4* p = partials + (size_t)row * 8;
    float m = -INFINITY;
#pragma unroll
    for (int i = 0; i < 8; ++i) {
        float4 v = p[i];
        m = fmaxf(m, fmaxf(fmaxf(v.x, v.y), fmaxf(v.z, v.w)));
    }
    out[row] = m;
}

// ---------------------------------------------------------------------------
extern "C" void kernel_launch(void* const* d_in, const int* in_sizes, int n_in,
                              void* d_out, int out_size, void* d_ws, size_t ws_size,
                              hipStream_t stream) {
    const float* x   = (const float*)d_in[0];
    const float* l1w = (const float*)d_in[1];
    const float* l1b = (const float*)d_in[2];
    const float* w2  = (const float*)d_in[3];
    const float* b2  = (const float*)d_in[4];
    float* out = (float*)d_out;

    char* ws = (char*)d_ws;
    // workspace layout (bytes)
    unsigned short* xb  = (unsigned short*)(ws);                 // 32 MB  x  bf16
    unsigned short* w1b = (unsigned short*)(ws + 33554432);      //  1 MB  l1_w bf16
    unsigned short* w2b = (unsigned short*)(ws + 34603008);      //  4 MB  weight bf16
    unsigned short* hb  = (unsigned short*)(ws + 38797312);      // 64 MB  h bf16
    float* partials     = (float*)(ws + 105906176);              //  4 MB  [BATCH,32]

    // 1) fp32 -> bf16 converts (x, l1_w, weight)
    cvt_kernel<<<18944, 256, 0, stream>>>(
        (const float4*)x, (const float4*)l1w, (const float4*)w2,
        (ushort4*)xb, (ushort4*)w1b, (ushort4*)w2b);

    // 2) h = x @ l1_w^T + l1_b   [32768, 1024]   (grid: N-fastest)
    gemm1_kernel<<<dim3(DHID / 128, BATCH / 128), 256, 0, stream>>>(xb, w1b, l1b, hb);

    // 3) scores = h @ weight^T + bias, fused per-block row-max (grid: N-fastest)
    gemm2_kernel<<<dim3(DOUT / 128, BATCH / 128), 256, 0, stream>>>(hb, w2b, b2, partials);

    // 4) final max over 32 partials per row
    reduce_kernel<<<BATCH / 256, 256, 0, stream>>>((const float4*)partials, out);
}

// Round 6
// 327.531 us; speedup vs baseline: 1.1937x; 1.0359x over previous
//
#include <hip/hip_runtime.h>
#include <hip/hip_bf16.h>
#include <stdint.h>

// Problem sizes (compile-time)
static constexpr int BATCH = 32768;
static constexpr int DIN   = 512;
static constexpr int DHID  = 1024;
static constexpr int DOUT  = 2048;

typedef __bf16 bf16x8 __attribute__((ext_vector_type(8)));
typedef float  f32x4  __attribute__((ext_vector_type(4)));

// fp32 -> bf16 round-to-nearest-even
__device__ __forceinline__ unsigned short f2bf(float f) {
    unsigned int u = __float_as_uint(f);
    u += 0x7FFFu + ((u >> 16) & 1u);
    return (unsigned short)(u >> 16);
}

// async global->LDS, 16B per lane. LDS dest = wave-uniform base + 16*lane.
__device__ __forceinline__ void gload_lds16(const void* g, void* l) {
    __builtin_amdgcn_global_load_lds((__attribute__((address_space(1))) void*)g,
                                     (__attribute__((address_space(3))) void*)l,
                                     16, 0, 0);
}

// ---------------------------------------------------------------------------
// Kernel 1: convert x, l1_w, weight fp32 -> bf16 into workspace
// ---------------------------------------------------------------------------
__global__ __launch_bounds__(256) void cvt_kernel(
    const float4* __restrict__ x, const float4* __restrict__ w1, const float4* __restrict__ w2,
    ushort4* __restrict__ xb, ushort4* __restrict__ w1b, ushort4* __restrict__ w2b) {
    const size_t NX  = (size_t)BATCH * DIN  / 4;
    const size_t NW1 = (size_t)DHID  * DIN  / 4;
    const size_t NW2 = (size_t)DOUT  * DHID / 4;
    size_t g = (size_t)blockIdx.x * blockDim.x + threadIdx.x;
    const float4* s; ushort4* d; size_t i;
    if (g < NX)                  { s = x;  d = xb;  i = g; }
    else if (g < NX + NW1)       { s = w1; d = w1b; i = g - NX; }
    else if (g < NX + NW1 + NW2) { s = w2; d = w2b; i = g - NX - NW1; }
    else return;
    float4 v = s[i];
    ushort4 o;
    o.x = f2bf(v.x); o.y = f2bf(v.y); o.z = f2bf(v.z); o.w = f2bf(v.w);
    d[i] = o;
}

// ===========================================================================
// Swizzled LDS tiles: row-major, 8 chunks(16B)/row (64 bf16),
//   slot(row, chunk) = row*8 + (chunk ^ (row&7)).
// Staging via global_load_lds: lane's chunk key (lane&7)^((lane>>3)&7) is
// issue-independent (rows advance by 8 per issue). Fragment reads use
// chunk = (ks*4+q) ^ (r&7) -> 8 lanes per 4-bank group; measured 0 conflicts.
// Grid is N-fastest for A-tile sharing among co-dispatched blocks.
// ===========================================================================

// ---------------------------------------------------------------------------
// GEMM1: h = x * l1_w^T + l1_b, bf16 out. BM=256, BN=128, BK=64.
// 4 waves in 2x2; wave tile 128x64 = 8x4 mfma_16x16x32 frags (64 MFMA/iter).
// ---------------------------------------------------------------------------
__global__ __launch_bounds__(256, 2) void gemm1_kernel(
    const unsigned short* __restrict__ A,   // x bf16 [BATCH, DIN]
    const unsigned short* __restrict__ Bw,  // l1_w bf16 [DHID, DIN]
    const float* __restrict__ l1b,          // [DHID]
    unsigned short* __restrict__ H) {       // out bf16 [BATCH, DHID]
    constexpr int K = DIN;
    __shared__ __align__(16) unsigned short sA[256 * 64];  // 32 KB
    __shared__ __align__(16) unsigned short sB[128 * 64];  // 16 KB

    const int tid  = threadIdx.x;
    const int lane = tid & 63;
    const int wid  = tid >> 6;
    const int wr = wid >> 1, wc = wid & 1;
    const int r = lane & 15, q = lane >> 4;
    const int sw = r & 7;
    const int blockN = blockIdx.x * 128;   // N-fastest
    const int blockM = blockIdx.y * 256;

    // staging bases (chunk key is issue-independent)
    const int chKey = (lane & 7) ^ ((lane >> 3) & 7);
    const size_t aBase = (size_t)(blockM + wid * 64 + (lane >> 3)) * K + chKey * 8;
    const size_t bBase = (size_t)(blockN + wid * 32 + (lane >> 3)) * K + chKey * 8;

    f32x4 acc[8][4];
#pragma unroll
    for (int mt = 0; mt < 8; ++mt)
#pragma unroll
        for (int nt = 0; nt < 4; ++nt) { f32x4 z = {0.f, 0.f, 0.f, 0.f}; acc[mt][nt] = z; }

    for (int k0 = 0; k0 < K; k0 += 64) {
#pragma unroll
        for (int j = 0; j < 8; ++j)    // A: 256 rows, 8 issues/thread
            gload_lds16(A + aBase + (size_t)j * 8 * K + k0, sA + wid * 4096 + j * 512);
#pragma unroll
        for (int j = 0; j < 4; ++j)    // B: 128 rows, 4 issues/thread
            gload_lds16(Bw + bBase + (size_t)j * 8 * K + k0, sB + wid * 2048 + j * 512);
        __syncthreads();
#pragma unroll
        for (int ks = 0; ks < 2; ++ks) {
            const int ch = ((ks << 2) + q) ^ sw;
            bf16x8 af[8], bf[4];
#pragma unroll
            for (int mt = 0; mt < 8; ++mt) af[mt] = *(const bf16x8*)&sA[(wr * 128 + mt * 16 + r) * 64 + ch * 8];
#pragma unroll
            for (int nt = 0; nt < 4; ++nt) bf[nt] = *(const bf16x8*)&sB[(wc * 64 + nt * 16 + r) * 64 + ch * 8];
#pragma unroll
            for (int mt = 0; mt < 8; ++mt)
#pragma unroll
                for (int nt = 0; nt < 4; ++nt)
                    acc[mt][nt] = __builtin_amdgcn_mfma_f32_16x16x32_bf16(af[mt], bf[nt], acc[mt][nt], 0, 0, 0);
        }
        __syncthreads();
    }

    // Epilogue: +bias, convert, store. C/D: col = lane&15, row = q*4+reg.
    const int colBase = blockN + wc * 64;
    const int rowBase = blockM + wr * 128;
    float bv[4];
#pragma unroll
    for (int nt = 0; nt < 4; ++nt) bv[nt] = l1b[colBase + nt * 16 + r];
#pragma unroll
    for (int mt = 0; mt < 8; ++mt) {
        const int row0 = rowBase + mt * 16 + q * 4;
#pragma unroll
        for (int nt = 0; nt < 4; ++nt) {
            const int col = colBase + nt * 16 + r;
#pragma unroll
            for (int reg = 0; reg < 4; ++reg)
                H[(size_t)(row0 + reg) * DHID + col] = f2bf(acc[mt][nt][reg] + bv[nt]);
        }
    }
}

// ---------------------------------------------------------------------------
// GEMM2: scores = H * weight^T + bias, fused row-max. 128x128, BK=64.
// Launched twice (M-halves) so the profile exposes the other kernels.
// ---------------------------------------------------------------------------
__global__ __launch_bounds__(256) void gemm2_kernel(
    const unsigned short* __restrict__ A,   // H bf16 [BATCH, DHID]
    const unsigned short* __restrict__ Bw,  // weight bf16 [DOUT, DHID]
    const float* __restrict__ bias,         // [DOUT]
    float* __restrict__ partials,           // [BATCH, 32]
    int mBase) {
    constexpr int K = DHID;
    __shared__ __align__(16) unsigned short sA[128 * 64];
    __shared__ __align__(16) unsigned short sB[128 * 64];

    const int tid  = threadIdx.x;
    const int lane = tid & 63;
    const int wid  = tid >> 6;
    const int wr = wid >> 1, wc = wid & 1;
    const int r = lane & 15, q = lane >> 4;
    const int sw = r & 7;
    const int blockN = blockIdx.x * 128;   // N-fastest
    const int blockM = mBase + blockIdx.y * 128;

    const int chKey = (lane & 7) ^ ((lane >> 3) & 7);
    const size_t aBase = (size_t)(blockM + wid * 32 + (lane >> 3)) * K + chKey * 8;
    const size_t bBase = (size_t)(blockN + wid * 32 + (lane >> 3)) * K + chKey * 8;

    f32x4 acc[4][4];
#pragma unroll
    for (int mt = 0; mt < 4; ++mt)
#pragma unroll
        for (int nt = 0; nt < 4; ++nt) { f32x4 z = {0.f, 0.f, 0.f, 0.f}; acc[mt][nt] = z; }

    for (int k0 = 0; k0 < K; k0 += 64) {
#pragma unroll
        for (int j = 0; j < 4; ++j) {
            gload_lds16(A  + aBase + (size_t)j * 8 * K + k0, sA + wid * 2048 + j * 512);
            gload_lds16(Bw + bBase + (size_t)j * 8 * K + k0, sB + wid * 2048 + j * 512);
        }
        __syncthreads();
#pragma unroll
        for (int ks = 0; ks < 2; ++ks) {
            const int ch = ((ks << 2) + q) ^ sw;
            bf16x8 af[4], bf[4];
#pragma unroll
            for (int mt = 0; mt < 4; ++mt) af[mt] = *(const bf16x8*)&sA[(wr * 64 + mt * 16 + r) * 64 + ch * 8];
#pragma unroll
            for (int nt = 0; nt < 4; ++nt) bf[nt] = *(const bf16x8*)&sB[(wc * 64 + nt * 16 + r) * 64 + ch * 8];
#pragma unroll
            for (int mt = 0; mt < 4; ++mt)
#pragma unroll
                for (int nt = 0; nt < 4; ++nt)
                    acc[mt][nt] = __builtin_amdgcn_mfma_f32_16x16x32_bf16(af[mt], bf[nt], acc[mt][nt], 0, 0, 0);
        }
        __syncthreads();
    }

    // Epilogue: +bias, max over the wave's 64 cols, 16-lane reduce, write partial.
    const int colBase = blockN + wc * 64;
    const int rowBase = blockM + wr * 64;
    float bv[4];
#pragma unroll
    for (int nt = 0; nt < 4; ++nt) bv[nt] = bias[colBase + nt * 16 + r];

    float mx[4][4];
#pragma unroll
    for (int mt = 0; mt < 4; ++mt)
#pragma unroll
        for (int reg = 0; reg < 4; ++reg) {
            float v = acc[mt][0][reg] + bv[0];
            v = fmaxf(v, acc[mt][1][reg] + bv[1]);
            v = fmaxf(v, acc[mt][2][reg] + bv[2]);
            v = fmaxf(v, acc[mt][3][reg] + bv[3]);
            mx[mt][reg] = v;
        }
#pragma unroll
    for (int off = 1; off < 16; off <<= 1)
#pragma unroll
        for (int mt = 0; mt < 4; ++mt)
#pragma unroll
            for (int reg = 0; reg < 4; ++reg)
                mx[mt][reg] = fmaxf(mx[mt][reg], __shfl_xor(mx[mt][reg], off));

    if (r == 0) {
#pragma unroll
        for (int mt = 0; mt < 4; ++mt)
#pragma unroll
            for (int reg = 0; reg < 4; ++reg) {
                const int row = rowBase + mt * 16 + q * 4 + reg;
                partials[(size_t)row * 32 + blockIdx.x * 2 + wc] = mx[mt][reg];
            }
    }
}

// ---------------------------------------------------------------------------
// Kernel 4: reduce 32 partials per row -> final max
// ---------------------------------------------------------------------------
__global__ __launch_bounds__(256) void reduce_kernel(
    const float4* __restrict__ partials, float* __restrict__ out) {
    const int row = blockIdx.x * blockDim.x + threadIdx.x;
    const float4* p = partials + (size_t)row * 8;
    float m = -INFINITY;
#pragma unroll
    for (int i = 0; i < 8; ++i) {
        float4 v = p[i];
        m = fmaxf(m, fmaxf(fmaxf(v.x, v.y), fmaxf(v.z, v.w)));
    }
    out[row] = m;
}

// ---------------------------------------------------------------------------
extern "C" void kernel_launch(void* const* d_in, const int* in_sizes, int n_in,
                              void* d_out, int out_size, void* d_ws, size_t ws_size,
                              hipStream_t stream) {
    const float* x   = (const float*)d_in[0];
    const float* l1w = (const float*)d_in[1];
    const float* l1b = (const float*)d_in[2];
    const float* w2  = (const float*)d_in[3];
    const float* b2  = (const float*)d_in[4];
    float* out = (float*)d_out;

    char* ws = (char*)d_ws;
    unsigned short* xb  = (unsigned short*)(ws);                 // 32 MB  x  bf16
    unsigned short* w1b = (unsigned short*)(ws + 33554432);      //  1 MB  l1_w bf16
    unsigned short* w2b = (unsigned short*)(ws + 34603008);      //  4 MB  weight bf16
    unsigned short* hb  = (unsigned short*)(ws + 38797312);      // 64 MB  h bf16
    float* partials     = (float*)(ws + 105906176);              //  4 MB  [BATCH,32]

    // 1) fp32 -> bf16 converts (x, l1_w, weight)
    cvt_kernel<<<18944, 256, 0, stream>>>(
        (const float4*)x, (const float4*)l1w, (const float4*)w2,
        (ushort4*)xb, (ushort4*)w1b, (ushort4*)w2b);

    // 2) h = x @ l1_w^T + l1_b   (BM=256, N-fastest grid)
    gemm1_kernel<<<dim3(DHID / 128, BATCH / 256), 256, 0, stream>>>(xb, w1b, l1b, hb);

    // 3) scores = h @ weight^T + bias, fused row-max — two M-half dispatches
    gemm2_kernel<<<dim3(DOUT / 128, BATCH / 256), 256, 0, stream>>>(hb, w2b, b2, partials, 0);
    gemm2_kernel<<<dim3(DOUT / 128, BATCH / 256), 256, 0, stream>>>(hb, w2b, b2, partials, BATCH / 2);

    // 4) final max over 32 partials per row
    reduce_kernel<<<BATCH / 256, 256, 0, stream>>>((const float4*)partials, out);
}